// Round 6
// baseline (860.106 us; speedup 1.0000x reference)
//
#include <hip/hip_runtime.h>
#include <hip/hip_bf16.h>

#define NUM_ADC_P 8
#define DENSE_L   1024
#define L_TILDE   64

#define M_TILE    64                      // rows per block (LDS kernel)
#define K_STEP    128                     // floats staged per step
#define N_STEPS   (DENSE_L / K_STEP)      // 8

typedef __attribute__((ext_vector_type(8))) short  short8;   // 8 bf16 (MFMA A/B frag)
typedef __attribute__((ext_vector_type(4))) float  float4v;  // MFMA C/D frag

// ws layout: [0, 128 KiB) = wt bf16[64][1024]  (Wt = W^T, n-major)

// ---------------------------------------------------------------------------
// DIAGNOSTIC ROUND: launches BOTH prior gemm structures back-to-back.
//   dur_R6 - dur_R5(724.3) = time of register-direct gemm
//   dur_R6 - dur_R3(719.3) = time of LDS-staged gemm
// Both kernels are verified-correct and write bitwise-identical output
// (same k-ascending summation order), so correctness is unaffected.
// This resolves the fill-vs-gemm decomposition ambiguity that has made
// three optimization rounds unattributable.
// ---------------------------------------------------------------------------

__global__ void build_w(const float* __restrict__ weight,
                        __hip_bfloat16* __restrict__ wt) {
    const int n = blockIdx.x;
    const float wn = weight[n];
    for (int k = threadIdx.x; k < DENSE_L; k += blockDim.x) {
        const float t = (float)(k + 1);
        const float d = t - wn;
        wt[n * DENSE_L + k] = __float2bfloat16(expf(-d * d * 0.01f));
    }
}

__device__ __forceinline__ short8 cvt8(float4v a, float4v b) {
    union { short8 s; __hip_bfloat162 h[4]; } u;
    u.h[0] = __float22bfloat162_rn(make_float2(a[0], a[1]));
    u.h[1] = __float22bfloat162_rn(make_float2(a[2], a[3]));
    u.h[2] = __float22bfloat162_rn(make_float2(b[0], b[1]));
    u.h[3] = __float22bfloat162_rn(make_float2(b[2], b[3]));
    return u.s;
}

__device__ __forceinline__ float4v ldnt(const float* p) {
    return __builtin_nontemporal_load((const float4v*)p);
}

// async global->LDS, 16 B per lane; LDS dest = wave-uniform base + lane*16
__device__ __forceinline__ void gload_lds16(const float* src, float* lds_dst) {
    __builtin_amdgcn_global_load_lds(
        (const __attribute__((address_space(1))) unsigned int*)src,
        (__attribute__((address_space(3))) unsigned int*)lds_dst,
        16, 0, 0);
}

// ---------------------------------------------------------------------------
// Variant 1 (R5): LDS-staged A via global_load_lds, m97 2-phase schedule.
// Measured (with harness fixed cost): 724.3 us total, absmax 0.125.
// ---------------------------------------------------------------------------
__global__ __launch_bounds__(256, 2)
void sampling_gemm_lds(const float* __restrict__ x,
                       const __hip_bfloat16* __restrict__ wt,
                       float* __restrict__ out) {
    __shared__ float A_lds[2][M_TILE * K_STEP];   // 2 x 32 KiB

    const int lane = threadIdx.x & 63;
    const int w    = threadIdx.x >> 6;            // wave 0..3
    const int r    = lane & 15;
    const int q    = lane >> 4;                   // quad 0..3
    const int half = lane >> 5;
    const int lc   = lane & 31;

    const long m0 = (long)blockIdx.x * M_TILE;
    const long mw = m0 + (long)w * 16;            // wave row base (16 rows/wave)

    const short* w0 = (const short*)wt + r * DENSE_L + q * 8;

    float4v acc[4];
    #pragma unroll
    for (int n = 0; n < 4; ++n) acc[n] = (float4v){0.f, 0.f, 0.f, 0.f};

    auto stage = [&](int step, int buf) {
        #pragma unroll
        for (int i = 0; i < 8; ++i) {
            const long row = mw + i * 2 + half;
            const float* src = x + row * DENSE_L + step * K_STEP + lc * 4;
            float* dst = &A_lds[buf][(w * 16 + i * 2) * K_STEP];
            gload_lds16(src, dst);
        }
    };

    stage(0, 0);
    __syncthreads();

    int cur = 0;
    for (int step = 0; step < N_STEPS; ++step) {
        short8 bfr[4][4];
        #pragma unroll
        for (int s = 0; s < 4; ++s) {
            const short* wk = w0 + (step * 4 + s) * 32;
            #pragma unroll
            for (int n = 0; n < 4; ++n)
                bfr[s][n] = *(const short8*)(wk + n * 16 * DENSE_L);
        }

        if (step < N_STEPS - 1)
            stage(step + 1, cur ^ 1);

        #pragma unroll
        for (int s = 0; s < 4; ++s) {
            const float* ap = &A_lds[cur][(w * 16 + r) * K_STEP + s * 32 + q * 8];
            const float4v alo = *(const float4v*)ap;
            const float4v ahi = *(const float4v*)(ap + 4);
            const short8 af = cvt8(alo, ahi);
            acc[0] = __builtin_amdgcn_mfma_f32_16x16x32_bf16(af, bfr[s][0], acc[0], 0, 0, 0);
            acc[1] = __builtin_amdgcn_mfma_f32_16x16x32_bf16(af, bfr[s][1], acc[1], 0, 0, 0);
            acc[2] = __builtin_amdgcn_mfma_f32_16x16x32_bf16(af, bfr[s][2], acc[2], 0, 0, 0);
            acc[3] = __builtin_amdgcn_mfma_f32_16x16x32_bf16(af, bfr[s][3], acc[3], 0, 0, 0);
        }

        __syncthreads();
        cur ^= 1;
    }

    #pragma unroll
    for (int ns = 0; ns < 4; ++ns) {
        #pragma unroll
        for (int rr = 0; rr < 4; ++rr) {
            __builtin_nontemporal_store(
                acc[ns][rr],
                out + (mw + q * 4 + rr) * L_TILDE + ns * 16 + r);
        }
    }
}

// ---------------------------------------------------------------------------
// Variant 2 (R3): register-direct, straight-line, B-before-A-prefetch vmcnt
// ladder. Measured (with harness fixed cost): 719.3 us total, absmax 0.125.
// Writes bitwise-identical output to variant 1 (same k-order summation).
// ---------------------------------------------------------------------------
__global__ __launch_bounds__(256, 4)
void sampling_gemm_reg(const float* __restrict__ x,
                       const __hip_bfloat16* __restrict__ wt,
                       float* __restrict__ out) {
    const int lane = threadIdx.x & 63;
    const int wave = threadIdx.x >> 6;                    // 0..3
    const int r    = lane & 15;
    const int q    = lane >> 4;                           // quad 0..3

    const long m0 = (long)blockIdx.x * 128 + (long)wave * 32;

    const float* a0 = x + (m0 + r) * DENSE_L + q * 8;     // m-subtile 0 row
    const float* a1 = a0 + 16 * DENSE_L;                  // m-subtile 1 row
    const short* w0 = (const short*)wt + r * DENSE_L + q * 8;

    float4v acc[2][4];
    #pragma unroll
    for (int i = 0; i < 2; ++i)
        #pragma unroll
        for (int j = 0; j < 4; ++j)
            acc[i][j] = (float4v){0.f, 0.f, 0.f, 0.f};

    float4v c0a = ldnt(a0), c0b = ldnt(a0 + 4);
    float4v c1a = ldnt(a1), c1b = ldnt(a1 + 4);

    for (int kk = 0; kk < 32; ++kk) {
        // B loads first (oldest in vmcnt FIFO -> counted waits, no drain)
        const short* wk = w0 + kk * 32;
        const short8 b0 = *(const short8*)(wk);
        const short8 b1 = *(const short8*)(wk + 16 * DENSE_L);
        const short8 b2 = *(const short8*)(wk + 32 * DENSE_L);
        const short8 b3 = *(const short8*)(wk + 48 * DENSE_L);

        const int kn = (kk + 1) & 31;                     // wraps: harmless reload
        const float4v n0a = ldnt(a0 + kn * 32);
        const float4v n0b = ldnt(a0 + kn * 32 + 4);
        const float4v n1a = ldnt(a1 + kn * 32);
        const float4v n1b = ldnt(a1 + kn * 32 + 4);

        const short8 af0 = cvt8(c0a, c0b);
        const short8 af1 = cvt8(c1a, c1b);

        acc[0][0] = __builtin_amdgcn_mfma_f32_16x16x32_bf16(af0, b0, acc[0][0], 0, 0, 0);
        acc[1][0] = __builtin_amdgcn_mfma_f32_16x16x32_bf16(af1, b0, acc[1][0], 0, 0, 0);
        acc[0][1] = __builtin_amdgcn_mfma_f32_16x16x32_bf16(af0, b1, acc[0][1], 0, 0, 0);
        acc[1][1] = __builtin_amdgcn_mfma_f32_16x16x32_bf16(af1, b1, acc[1][1], 0, 0, 0);
        acc[0][2] = __builtin_amdgcn_mfma_f32_16x16x32_bf16(af0, b2, acc[0][2], 0, 0, 0);
        acc[1][2] = __builtin_amdgcn_mfma_f32_16x16x32_bf16(af1, b2, acc[1][2], 0, 0, 0);
        acc[0][3] = __builtin_amdgcn_mfma_f32_16x16x32_bf16(af0, b3, acc[0][3], 0, 0, 0);
        acc[1][3] = __builtin_amdgcn_mfma_f32_16x16x32_bf16(af1, b3, acc[1][3], 0, 0, 0);

        c0a = n0a; c0b = n0b; c1a = n1a; c1b = n1b;
    }

    #pragma unroll
    for (int ms = 0; ms < 2; ++ms) {
        #pragma unroll
        for (int ns = 0; ns < 4; ++ns) {
            #pragma unroll
            for (int rr = 0; rr < 4; ++rr) {
                __builtin_nontemporal_store(
                    acc[ms][ns][rr],
                    out + (m0 + ms * 16 + q * 4 + rr) * L_TILDE + ns * 16 + r);
            }
        }
    }
}

// ---------------------------------------------------------------------------
extern "C" void kernel_launch(void* const* d_in, const int* in_sizes, int n_in,
                              void* d_out, int out_size, void* d_ws, size_t ws_size,
                              hipStream_t stream) {
    const float* x      = (const float*)d_in[0];   // [B, P*L] fp32
    const float* weight = (const float*)d_in[1];   // [64] fp32
    float* out          = (float*)d_out;           // [B, P*64] fp32
    __hip_bfloat16* wt  = (__hip_bfloat16*)d_ws;   // [64][1024] bf16 = 128 KiB

    const int M = in_sizes[0] / DENSE_L;           // B * NUM_ADC_P = 131072

    build_w<<<64, 256, 0, stream>>>(weight, wt);
    // Variant 1 (R5 structure): total-time anchor vs R5's 724.3 us
    sampling_gemm_lds<<<M / M_TILE, 256, 0, stream>>>(x, wt, out);
    // Variant 2 (R3 structure): idempotent overwrite, identical values.
    // dur_R6 - 724.3 = this kernel's isolated time.
    sampling_gemm_reg<<<M / 128, 256, 0, stream>>>(x, wt, out);
}

// Round 10
// 703.245 us; speedup vs baseline: 1.2231x; 1.2231x over previous
//
#include <hip/hip_runtime.h>
#include <hip/hip_bf16.h>

#define NUM_ADC_P 8
#define DENSE_L   1024
#define L_TILDE   64

#define M_PER_BLOCK 512                   // rows per block (16 waves x 32 rows)
#define THREADS     1024

typedef __attribute__((ext_vector_type(8))) short  short8;   // 8 bf16 (MFMA A/B frag)
typedef __attribute__((ext_vector_type(4))) float  float4v;  // MFMA C/D frag

// ---------------------------------------------------------------------------
// Single mega-kernel (R7 structure, single-pass). Measurement model from the
// R6 diagnostic: dur_us = 583.5 (harness floor, cross-validated) + G_gemm.
// Prior structures: G_reg = 135.8 us, G_lds = 140.8 us = ~67% of the ~90 us
// HBM floor for 512 MiB read + 32 MiB write.
//
// Hypothesis under test: Wt B-loads sharing the vmcnt FIFO with the A stream
// force every counted B-wait to drain all older A prefetches (in-order
// completion), collapsing effective A prefetch depth. Fix: Wt lives in LDS
// (lgkmcnt domain) -> vmcnt FIFO is A-ONLY -> counted vmcnt waits keep the
// next A slabs in flight.
//   - Wt computed IN-KERNEL into XOR-swizzled LDS (128 KiB): no build_w
//     kernel, no global Wt traffic, one barrier total.
//   - 1024 thr (16 waves), grid = 256 = 1 block/CU; launch_bounds(1024,4)
//     -> VGPR cap 128 (est. ~110).
//   - Swizzle byte ^= (row&7)<<4 applied identically on write and read
//     (same involution both sides); B-frag ds_read_b128 lands 2 lanes per
//     16-B slot within each 16-lane phase -> 2-way = free (m136).
//
// Fragment layout (verified, absmax 0.125):
//   A frag: lane holds A[m0 + (lane&15)][32*kk + (lane>>4)*8 + j], j=0..7
//   B frag: lane holds Wt[n0 + (lane&15)][32*kk + (lane>>4)*8 + j]
//   D frag: D[m0 + (lane>>4)*4 + rr][n0 + (lane&15)], rr=0..3
// ---------------------------------------------------------------------------

__device__ __forceinline__ short8 cvt8(float4v a, float4v b) {
    union { short8 s; __hip_bfloat162 h[4]; } u;
    u.h[0] = __float22bfloat162_rn(make_float2(a[0], a[1]));
    u.h[1] = __float22bfloat162_rn(make_float2(a[2], a[3]));
    u.h[2] = __float22bfloat162_rn(make_float2(b[0], b[1]));
    u.h[3] = __float22bfloat162_rn(make_float2(b[2], b[3]));
    return u.s;
}

__device__ __forceinline__ float4v ldnt(const float* p) {
    return __builtin_nontemporal_load((const float4v*)p);
}

__global__ __launch_bounds__(THREADS, 4)
void sampling_gemm(const float* __restrict__ x,
                   const float* __restrict__ weight,
                   float* __restrict__ out) {
    __shared__ short Wt[64 * DENSE_L];            // 128 KiB, swizzled bf16
    char* wtb = (char*)Wt;

    const int tid = threadIdx.x;

    // ---- Wt init: thread (n = tid>>4) covers k in [ (tid&15)*64, +64 ) ----
    {
        const int n  = tid >> 4;                  // 0..63
        const int k0 = (tid & 15) * 64;
        const float wn = weight[n];
        const int xr = (n & 7) << 4;
        #pragma unroll 8
        for (int j = 0; j < 64; ++j) {
            const int k = k0 + j;
            const float d = (float)(k + 1) - wn;
            const int byte = (n * 2048 + k * 2) ^ xr;
            *(__hip_bfloat16*)(wtb + byte) = __float2bfloat16(expf(-d * d * 0.01f));
        }
    }
    __syncthreads();                              // the ONLY barrier

    const int lane = tid & 63;
    const int wave = tid >> 6;                    // 0..15
    const int r    = lane & 15;
    const int q    = lane >> 4;                   // quad 0..3

    const long m0 = (long)blockIdx.x * M_PER_BLOCK + (long)wave * 32;

    const float* a0 = x + (m0 + r) * DENSE_L + q * 8;   // m-subtile 0 row
    const float* a1 = a0 + 16 * DENSE_L;                // m-subtile 1 row

    // B-frag LDS addressing: lin(ns,kk) = (ns*16+r)*2048 + kk*64 + q*16,
    // read addr = lin ^ xmask (xmask = (r&7)<<4, matching the write side).
    const int xmask = (r & 7) << 4;
    const int bbase = r * 2048 + q * 16;

    float4v acc[2][4];
    #pragma unroll
    for (int i = 0; i < 2; ++i)
        #pragma unroll
        for (int j = 0; j < 4; ++j)
            acc[i][j] = (float4v){0.f, 0.f, 0.f, 0.f};

    // prologue: E = slab 0, O = slab 1 (depth-2, A-only vmcnt FIFO)
    float4v e0a = ldnt(a0),      e0b = ldnt(a0 + 4);
    float4v e1a = ldnt(a1),      e1b = ldnt(a1 + 4);
    float4v o0a = ldnt(a0 + 32), o0b = ldnt(a0 + 36);
    float4v o1a = ldnt(a1 + 32), o1b = ldnt(a1 + 36);

    // consume slabs t,t+1; prefetch t+2,t+3 (covers 2..31 exactly)
    for (int t = 0; t < 30; t += 2) {
        { // even slab t: consume E (vmcnt counted: O still in flight)
            const short8 af0 = cvt8(e0a, e0b);
            const short8 af1 = cvt8(e1a, e1b);
            e0a = ldnt(a0 + (t + 2) * 32); e0b = ldnt(a0 + (t + 2) * 32 + 4);
            e1a = ldnt(a1 + (t + 2) * 32); e1b = ldnt(a1 + (t + 2) * 32 + 4);
            #pragma unroll
            for (int ns = 0; ns < 4; ++ns) {
                const short8 bf = *(const short8*)(
                    wtb + ((bbase + ns * 32768 + t * 64) ^ xmask));
                acc[0][ns] = __builtin_amdgcn_mfma_f32_16x16x32_bf16(af0, bf, acc[0][ns], 0, 0, 0);
                acc[1][ns] = __builtin_amdgcn_mfma_f32_16x16x32_bf16(af1, bf, acc[1][ns], 0, 0, 0);
            }
        }
        { // odd slab t+1: consume O (new E in flight)
            const short8 af0 = cvt8(o0a, o0b);
            const short8 af1 = cvt8(o1a, o1b);
            o0a = ldnt(a0 + (t + 3) * 32); o0b = ldnt(a0 + (t + 3) * 32 + 4);
            o1a = ldnt(a1 + (t + 3) * 32); o1b = ldnt(a1 + (t + 3) * 32 + 4);
            #pragma unroll
            for (int ns = 0; ns < 4; ++ns) {
                const short8 bf = *(const short8*)(
                    wtb + ((bbase + ns * 32768 + (t + 1) * 64) ^ xmask));
                acc[0][ns] = __builtin_amdgcn_mfma_f32_16x16x32_bf16(af0, bf, acc[0][ns], 0, 0, 0);
                acc[1][ns] = __builtin_amdgcn_mfma_f32_16x16x32_bf16(af1, bf, acc[1][ns], 0, 0, 0);
            }
        }
    }
    { // epilogue slab 30 (E)
        const short8 af0 = cvt8(e0a, e0b);
        const short8 af1 = cvt8(e1a, e1b);
        #pragma unroll
        for (int ns = 0; ns < 4; ++ns) {
            const short8 bf = *(const short8*)(
                wtb + ((bbase + ns * 32768 + 30 * 64) ^ xmask));
            acc[0][ns] = __builtin_amdgcn_mfma_f32_16x16x32_bf16(af0, bf, acc[0][ns], 0, 0, 0);
            acc[1][ns] = __builtin_amdgcn_mfma_f32_16x16x32_bf16(af1, bf, acc[1][ns], 0, 0, 0);
        }
    }
    { // epilogue slab 31 (O)
        const short8 af0 = cvt8(o0a, o0b);
        const short8 af1 = cvt8(o1a, o1b);
        #pragma unroll
        for (int ns = 0; ns < 4; ++ns) {
            const short8 bf = *(const short8*)(
                wtb + ((bbase + ns * 32768 + 31 * 64) ^ xmask));
            acc[0][ns] = __builtin_amdgcn_mfma_f32_16x16x32_bf16(af0, bf, acc[0][ns], 0, 0, 0);
            acc[1][ns] = __builtin_amdgcn_mfma_f32_16x16x32_bf16(af1, bf, acc[1][ns], 0, 0, 0);
        }
    }

    // Stores: D[m0 + ms*16 + q*4 + rr][ns*16 + r]; streaming.
    #pragma unroll
    for (int ms = 0; ms < 2; ++ms) {
        #pragma unroll
        for (int ns = 0; ns < 4; ++ns) {
            #pragma unroll
            for (int rr = 0; rr < 4; ++rr) {
                __builtin_nontemporal_store(
                    acc[ms][ns][rr],
                    out + (m0 + ms * 16 + q * 4 + rr) * L_TILDE + ns * 16 + r);
            }
        }
    }
}

// ---------------------------------------------------------------------------
extern "C" void kernel_launch(void* const* d_in, const int* in_sizes, int n_in,
                              void* d_out, int out_size, void* d_ws, size_t ws_size,
                              hipStream_t stream) {
    const float* x      = (const float*)d_in[0];   // [B, P*L] fp32
    const float* weight = (const float*)d_in[1];   // [64] fp32
    float* out          = (float*)d_out;           // [B, P*64] fp32
    (void)d_ws; (void)ws_size;                     // workspace unused

    const int M = in_sizes[0] / DENSE_L;           // B * NUM_ADC_P = 131072
    const int grid = M / M_PER_BLOCK;              // 256 blocks = 1/CU

    sampling_gemm<<<grid, THREADS, 0, stream>>>(x, weight, out);
}